// Round 13
// baseline (5787.424 us; speedup 1.0000x reference)
//
#include <hip/hip_runtime.h>
#include <math.h>

#define Bsz 128
#define Tsz 512
#define Esz 512
#define Hsz 1024
#define G4H 4096
#define Vsz 32000
#define NB  64           // lstm blocks (16 j-cols each)
#define BH  (Bsz * Hsz)
#define XPS 68           // padded xps row stride (shorts)

typedef __attribute__((ext_vector_type(8))) short short8;
typedef __attribute__((ext_vector_type(4))) short short4v;
typedef __attribute__((ext_vector_type(8))) __bf16 bf16x8;
typedef __attribute__((ext_vector_type(16))) float f32x16;
typedef __attribute__((ext_vector_type(4))) float f32x4;
typedef __attribute__((ext_vector_type(4))) unsigned int uint4v;

__device__ inline unsigned short f2bf(float f) {
    unsigned u = __float_as_uint(f);
    u += 0x7fffu + ((u >> 16) & 1u);   // RTNE
    return (unsigned short)(u >> 16);
}
__device__ inline float bf2f(unsigned short s) {
    return __uint_as_float(((unsigned)s) << 16);
}
__device__ inline f32x4 mfma16(short8 a, short8 b, f32x4 c) {
    return __builtin_amdgcn_mfma_f32_16x16x32_bf16(
        __builtin_bit_cast(bf16x8, a), __builtin_bit_cast(bf16x8, b), c, 0, 0, 0);
}
__device__ inline f32x16 mfma32(short8 a, short8 b, f32x16 c) {
    return __builtin_amdgcn_mfma_f32_32x32x16_bf16(
        __builtin_bit_cast(bf16x8, a), __builtin_bit_cast(bf16x8, b), c, 0, 0, 0);
}

// async 16B loads; early-clobber so dst never aliases addr regs
#define GLD16P(dst, p)  asm volatile("global_load_dwordx4 %0, %1, off"         : "=&v"(dst) : "v"(p))
#define GLD16C(dst, p)  asm volatile("global_load_dwordx4 %0, %1, off sc0 sc1" : "=&v"(dst) : "v"(p))

#define WAITVM(n)                                                          \
    do { asm volatile("s_waitcnt vmcnt(" #n ")" ::: "memory");             \
         __builtin_amdgcn_sched_barrier(0); } while (0)

// MALL-coherent scalar flag ops (proven R11)
__device__ inline unsigned ld_flag(const unsigned* p) {
    unsigned r;
    asm volatile("global_load_dword %0, %1, off sc0 sc1\n\ts_waitcnt vmcnt(0)"
                 : "=&v"(r) : "v"(p) : "memory");
    return r;
}
__device__ inline void st_flag(unsigned* p, unsigned v) {
    asm volatile("global_store_dword %0, %1, off sc0 sc1" :: "v"(p), "v"(v) : "memory");
}

// ---------------- prep kernels ----------------
__global__ void k_prep_emb(const float* __restrict__ emb, unsigned short* __restrict__ dst) {
    size_t i = (size_t)blockIdx.x * 256 + threadIdx.x;
    if (i < (size_t)Vsz * Esz) dst[i] = f2bf(i < Esz ? 0.f : emb[i]);  // row 0 = PAD -> 0
}

__global__ void k_prep_w(const float* __restrict__ wi, const float* __restrict__ wf,
                         const float* __restrict__ wg, const float* __restrict__ wo,
                         int ncols, unsigned short* __restrict__ dst) {
    size_t i = (size_t)blockIdx.x * 256 + threadIdx.x;
    size_t per = (size_t)Hsz * ncols;
    if (i < 4 * per) {
        int g = (int)(i / per);
        size_t rem = i - (size_t)g * per;
        const float* src = g == 0 ? wi : g == 1 ? wf : g == 2 ? wg : wo;
        dst[i] = f2bf(src[rem]);
    }
}

__global__ void k_prep_misc(const float* __restrict__ bi, const float* __restrict__ bff,
                            const float* __restrict__ bg, const float* __restrict__ bo,
                            float* __restrict__ b4, unsigned short* __restrict__ ghbuf,
                            float* __restrict__ cbuf, float* __restrict__ outh,
                            unsigned* __restrict__ flags) {
    int i = blockIdx.x * 256 + threadIdx.x;
    if (i < G4H) {
        const float* src = i < Hsz ? bi : i < 2 * Hsz ? bff : i < 3 * Hsz ? bg : bo;
        b4[i] = src[i & (Hsz - 1)];
    }
    if (i < 2 * BH) ghbuf[i] = 0;
    if (i < BH) { cbuf[i] = 0.f; outh[i] = 0.f; }
    if (i < NB * 32) flags[i] = 0u;
}

// ---------------- xp = emb[x] @ Wi^T + b  (layout [t'][bk64][b][jj16][gate4]) ----------------
__global__ __launch_bounds__(256, 2) void xp_gemm(
    const unsigned short* __restrict__ emb16, const unsigned short* __restrict__ Wi16,
    const float* __restrict__ b4, const int* __restrict__ x,
    unsigned short* __restrict__ xp, int t_base)
{
    const int tp = blockIdx.x;
    const int n0 = blockIdx.y * 128;
    const int tid = threadIdx.x;
    const int w = tid >> 6, l = tid & 63;
    const int wm = w >> 1, wn = w & 1;
    const int lr = l & 15, lk = l >> 4;

    const unsigned short* arow[4];
    #pragma unroll
    for (int mt = 0; mt < 4; ++mt) {
        int b = wm * 64 + mt * 16 + lr;
        int xv = x[b * Tsz + t_base + tp];
        arow[mt] = emb16 + (size_t)xv * Esz + lk * 8;
    }
    const unsigned short* brow[4];
    #pragma unroll
    for (int nt = 0; nt < 4; ++nt) {
        int n = n0 + wn * 64 + nt * 16 + lr;
        brow[nt] = Wi16 + (size_t)n * Esz + lk * 8;
    }
    f32x4 acc[4][4] = {};
    #pragma unroll 2
    for (int k0 = 0; k0 < Esz; k0 += 32) {
        short8 av[4], bv[4];
        #pragma unroll
        for (int mt = 0; mt < 4; ++mt) av[mt] = *(const short8*)(arow[mt] + k0);
        #pragma unroll
        for (int nt = 0; nt < 4; ++nt) bv[nt] = *(const short8*)(brow[nt] + k0);
        #pragma unroll
        for (int mt = 0; mt < 4; ++mt)
            #pragma unroll
            for (int nt = 0; nt < 4; ++nt)
                acc[mt][nt] = mfma16(av[mt], bv[nt], acc[mt][nt]);
    }
    #pragma unroll
    for (int nt = 0; nt < 4; ++nt) {
        int n = n0 + wn * 64 + nt * 16 + lr;
        float bias = b4[n];
        int g = n >> 10, j = n & 1023;
        int bk = j >> 4, jj = j & 15;
        #pragma unroll
        for (int mt = 0; mt < 4; ++mt) {
            #pragma unroll
            for (int r = 0; r < 4; ++r) {
                int b = wm * 64 + mt * 16 + lk * 4 + r;
                xp[((size_t)tp * NB + bk) * (Bsz * 64) + b * 64 + jj * 4 + g] =
                    f2bf(acc[mt][nt][r] + bias);
            }
        }
    }
}

// ---------------- fused recurrence ----------------
// 64 blocks x 4 waves (256 thr), 32x32x16 MFMA. Block owns 16 j-cols x 4 gates
// = 64 Wh rows in LDS. Wave w: M=32 rows x 2 N-tiles (nt0 = cols 0-31 = gates
// i,f ; nt1 = 32-63 = g,o). Per k-step: 1 A-load (1KB contiguous/wave) + 2
// ds_read_b128 + 2 MFMA -> LDS B-reads halved vs R11, A-traffic unchanged.
// 4-deep chunk pipeline (32KB outstanding/CU ~ BDP) covers MALL latency.
// h: ghbuf[2][slab=64][b=128][16], sc0sc1 MALL exchange; flag sync (R11-proven).
__global__ __launch_bounds__(256, 1) void lstm_steps(
    const unsigned short* __restrict__ Wh16,
    const unsigned short* __restrict__ xp,    // [T'][NB][b][16][4] bf16
    const int* __restrict__ lengths,
    unsigned short* __restrict__ ghbuf,       // [2][64][128][16] bf16 double buffer
    float* __restrict__ cbuf,
    float* __restrict__ outh,
    unsigned* __restrict__ flags,             // [64] seqno flags, stride 32 u32
    int t0, int nsteps)
{
    __shared__ unsigned short Whs[64][1032];   // 129 KB
    __shared__ unsigned short xps[Bsz * XPS];  // 17 KB
    __shared__ unsigned short hls[Bsz * 16];   // 4 KB
    const int tid = threadIdx.x;
    const int blk = blockIdx.x;
    const int j0 = blk * 16;

    // stage Wh slice: local row n -> gate n>>4, col j0+(n&15)
    for (int idx = tid; idx < 64 * 128; idx += 256) {
        int n = idx >> 7, gq = idx & 127;
        int grow = (n >> 4) * Hsz + j0 + (n & 15);
        *(short8*)&Whs[n][gq << 3] =
            *(const short8*)(Wh16 + (size_t)grow * Hsz + gq * 8);
    }

    const int w = tid >> 6, l = tid & 63;
    const int c31 = l & 31, jj = l & 15;
    const int hi = (l >> 5) & 1;               // k-half / row +4
    const int hib = (l >> 4) & 1;              // col>=16 -> f/o owner, rows +16
    const bool lo = (hib == 0);

    // lane owns 8 (b, jj) cells: q=0..7 -> row = (q&3) + 8*(q>>2) + 4*hi + 16*hib
    int lenr[8];
    float creg[8];
    #pragma unroll
    for (int q = 0; q < 8; ++q) {
        int row = (q & 3) + ((q >> 2) << 3) + (hi << 2) + (hib << 4);
        int b = 32 * w + row;
        lenr[q] = lengths[b];
        creg[q] = cbuf[(size_t)b * Hsz + j0 + jj];
    }

    // prologue: stage xp slice for s=0 — EXACT mirror of the in-loop restage:
    // thread tid covers xp shorts [tid*32, tid*32+32) -> xps[(tid>>1)*XPS + (tid&1)*32]
    {
        const unsigned short* sp = xp + (size_t)blk * (Bsz * 64) + tid * 32;
        int xb = tid >> 1, xq = tid & 1;
        unsigned short* d = &xps[xb * XPS + xq * 32];
        #pragma unroll
        for (int u = 0; u < 4; ++u)
            *(short8*)(d + u * 8) = *(const short8*)(sp + u * 8);
    }
    __syncthreads();

    // A-load lane base: slab*2048 + b*16 + hi*8 shorts; b = 32w + c31
    const int hb_off = (32 * w + c31) * 16 + hi * 8;
    const int bko = hi * 8;                    // B k-half offset (shorts)

#define ISSUE_CHUNK(buf, kc_) do {                                         \
        GLD16C(buf[0], hb + (kc_) * 16384 + 0 * 2048);                     \
        GLD16C(buf[1], hb + (kc_) * 16384 + 1 * 2048);                     \
        GLD16C(buf[2], hb + (kc_) * 16384 + 2 * 2048);                     \
        GLD16C(buf[3], hb + (kc_) * 16384 + 3 * 2048);                     \
        GLD16C(buf[4], hb + (kc_) * 16384 + 4 * 2048);                     \
        GLD16C(buf[5], hb + (kc_) * 16384 + 5 * 2048);                     \
        GLD16C(buf[6], hb + (kc_) * 16384 + 6 * 2048);                     \
        GLD16C(buf[7], hb + (kc_) * 16384 + 7 * 2048);                     \
    } while (0)

#define CONSUME(buf, kc_) do {                                             \
        _Pragma("unroll")                                                  \
        for (int ks_ = 0; ks_ < 8; ++ks_) {                                \
            short8 a_ = __builtin_bit_cast(short8, buf[ks_]);              \
            const int ko_ = ((kc_) * 8 + ks_) * 16 + bko;                  \
            short8 b0_ = *(const short8*)&Whs[c31][ko_];                   \
            short8 b1_ = *(const short8*)&Whs[32 + c31][ko_];              \
            acc0 = mfma32(a_, b0_, acc0);                                  \
            acc1 = mfma32(a_, b1_, acc1);                                  \
        }                                                                  \
    } while (0)

    for (int s = 0; s < nsteps; ++s) {
        const int t = t0 + s;
        const unsigned short* hb = ghbuf + (size_t)(t & 1) * BH + hb_off;
        int sn = (s + 1 < nsteps) ? s + 1 : s;
        const unsigned short* xpn = xp + ((size_t)sn * NB + blk) * (Bsz * 64) + tid * 32;

        f32x16 acc0 = {}, acc1 = {};
        uint4v P[8], Q[8], R[8], S[8], xr0, xr1, xr2, xr3;
        // 4-deep chunk pipeline (32 loads in flight)
        ISSUE_CHUNK(P, 0); ISSUE_CHUNK(Q, 1); ISSUE_CHUNK(R, 2); ISSUE_CHUNK(S, 3);
        WAITVM(24); CONSUME(P, 0); ISSUE_CHUNK(P, 4);
        WAITVM(24); CONSUME(Q, 1); ISSUE_CHUNK(Q, 5);
        WAITVM(24); CONSUME(R, 2); ISSUE_CHUNK(R, 6);
        WAITVM(24); CONSUME(S, 3); ISSUE_CHUNK(S, 7);
        WAITVM(24); CONSUME(P, 4);
        GLD16P(xr0, xpn); GLD16P(xr1, xpn + 8);
        GLD16P(xr2, xpn + 16); GLD16P(xr3, xpn + 24);
        WAITVM(20); CONSUME(Q, 5);
        WAITVM(12); CONSUME(R, 6);
        WAITVM(4);  CONSUME(S, 7);             // xr still in flight

        // gates: full-lane via shfl_xor(16) pairing; lo lanes use regs q, hi q+8
        #pragma unroll
        for (int q = 0; q < 8; ++q) {
            float r0a = __shfl_xor(acc0[q], 16);
            float r0b = __shfl_xor(acc0[q + 8], 16);
            float r1a = __shfl_xor(acc1[q], 16);
            float r1b = __shfl_xor(acc1[q + 8], 16);
            float zi = lo ? acc0[q]     : r0b;
            float zf = lo ? r0a         : acc0[q + 8];
            float zg = lo ? acc1[q]     : r1b;
            float zo = lo ? r1a         : acc1[q + 8];
            int row = (q & 3) + ((q >> 2) << 3) + (hi << 2) + (hib << 4);
            int b = 32 * w + row;
            short4v xg4 = *(const short4v*)&xps[b * XPS + jj * 4];
            zi += bf2f((unsigned short)xg4[0]);
            zf += bf2f((unsigned short)xg4[1]);
            zg += bf2f((unsigned short)xg4[2]);
            zo += bf2f((unsigned short)xg4[3]);
            float it = 1.f / (1.f + __expf(-zi));
            float ft = 1.f / (1.f + __expf(-zf));
            float gt = tanhf(zg);
            float ot = 1.f / (1.f + __expf(-zo));
            float c = ft * creg[q] + it * gt;
            creg[q] = c;
            float h = ot * tanhf(c);
            if (lenr[q] == t + 1) outh[(size_t)b * Hsz + j0 + jj] = h;
            hls[b * 16 + jj] = f2bf(h);
        }
        __syncthreads();   // hls complete; xps reads for step s done

        // coalesced h slab store: one contiguous 4KB burst, write-through to MALL
        unsigned short* ghn = ghbuf + (size_t)((t + 1) & 1) * BH;
        {
            short8 hv8 = *(const short8*)&hls[tid * 8];
            unsigned short* hd = ghn + (size_t)blk * 2048 + tid * 8;
            asm volatile("global_store_dwordx4 %0, %1, off sc0 sc1"
                         :: "v"(hd), "v"(__builtin_bit_cast(uint4v, hv8)) : "memory");
        }

        // drain stores + xr, restage xps from prefetched regs
        WAITVM(0);
        {
            int xb = tid >> 1, xq = tid & 1;
            unsigned short* d = &xps[xb * XPS + xq * 32];
            *(short8*)(d + 0)  = __builtin_bit_cast(short8, xr0);
            *(short8*)(d + 8)  = __builtin_bit_cast(short8, xr1);
            *(short8*)(d + 16) = __builtin_bit_cast(short8, xr2);
            *(short8*)(d + 24) = __builtin_bit_cast(short8, xr3);
        }
        __syncthreads();   // all threads' slab stores ACKed at MALL; xps staged

        // ---- decentralized sync: post own seqno, poll all 64 (R11-proven) ----
        if (tid == 0) st_flag(&flags[blk * 32], (unsigned)(t + 1));
        {
            const unsigned* fp = &flags[(tid & 63) * 32];
            while (ld_flag(fp) < (unsigned)(t + 1)) __builtin_amdgcn_s_sleep(1);
        }
        __syncthreads();
        __builtin_amdgcn_sched_barrier(0);
    }

    #pragma unroll
    for (int q = 0; q < 8; ++q) {
        int row = (q & 3) + ((q >> 2) << 3) + (hi << 2) + (hib << 4);
        int b = 32 * w + row;
        cbuf[(size_t)b * Hsz + j0 + jj] = creg[q];
    }
#undef ISSUE_CHUNK
#undef CONSUME
}

// ---------------- final fc ----------------
__global__ __launch_bounds__(64) void k_fc(const float* __restrict__ outh,
                                           const float* __restrict__ fc_w,
                                           const float* __restrict__ fc_b,
                                           float* __restrict__ out) {
    int b = blockIdx.x, l = threadIdx.x;
    float s = 0.f;
    for (int k = l; k < Hsz; k += 64) s += outh[(size_t)b * Hsz + k] * fc_w[k];
    #pragma unroll
    for (int o = 32; o > 0; o >>= 1) s += __shfl_down(s, o);
    if (l == 0) out[b] = s + fc_b[0];
}

extern "C" void kernel_launch(void* const* d_in, const int* in_sizes, int n_in,
                              void* d_out, int out_size, void* d_ws, size_t ws_size,
                              hipStream_t stream) {
    const int* x       = (const int*)d_in[0];
    const int* lengths = (const int*)d_in[1];
    const float* emb   = (const float*)d_in[2];
    const float* W_ii  = (const float*)d_in[3];
    const float* W_hi  = (const float*)d_in[4];
    const float* b_i   = (const float*)d_in[5];
    const float* W_if  = (const float*)d_in[6];
    const float* W_hf  = (const float*)d_in[7];
    const float* b_f   = (const float*)d_in[8];
    const float* W_ig  = (const float*)d_in[9];
    const float* W_hg  = (const float*)d_in[10];
    const float* b_g   = (const float*)d_in[11];
    const float* W_io  = (const float*)d_in[12];
    const float* W_ho  = (const float*)d_in[13];
    const float* b_o   = (const float*)d_in[14];
    const float* fc_w  = (const float*)d_in[15];
    const float* fc_b  = (const float*)d_in[16];
    float* out = (float*)d_out;

    char* ws = (char*)d_ws;
    size_t off = 0;
    auto take = [&](size_t bytes) { size_t o = off; off += (bytes + 255) & ~(size_t)255; return o; };
    unsigned* flags       = (unsigned*)(ws + take((size_t)NB * 128));
    unsigned short* ghbuf = (unsigned short*)(ws + take((size_t)2 * BH * 2));
    float* cbuf           = (float*)(ws + take((size_t)BH * 4));
    float* outh           = (float*)(ws + take((size_t)BH * 4));
    float* b4             = (float*)(ws + take((size_t)G4H * 4));
    unsigned short* Wi16  = (unsigned short*)(ws + take((size_t)G4H * Esz * 2));
    unsigned short* Wh16  = (unsigned short*)(ws + take((size_t)G4H * Hsz * 2));
    unsigned short* emb16 = (unsigned short*)(ws + take((size_t)Vsz * Esz * 2));
    size_t fixed = off;

    int TC = 128;
    while (TC > 1 && fixed + (size_t)TC * Bsz * G4H * 2 > ws_size) TC >>= 1;
    unsigned short* xp = (unsigned short*)(ws + take((size_t)TC * Bsz * G4H * 2));

    k_prep_emb<<<(Vsz * Esz + 255) / 256, 256, 0, stream>>>(emb, emb16);
    k_prep_w<<<(4 * Hsz * Esz + 255) / 256, 256, 0, stream>>>(W_ii, W_if, W_ig, W_io, Esz, Wi16);
    k_prep_w<<<(4 * Hsz * Hsz + 255) / 256, 256, 0, stream>>>(W_hi, W_hf, W_hg, W_ho, Hsz, Wh16);
    k_prep_misc<<<(2 * BH + 255) / 256, 256, 0, stream>>>(b_i, b_f, b_g, b_o, b4, ghbuf, cbuf, outh, flags);

    for (int c = 0; c < Tsz / TC; ++c) {
        dim3 g(TC, 32);
        xp_gemm<<<g, 256, 0, stream>>>(emb16, Wi16, b4, x, xp, c * TC);
        lstm_steps<<<NB, 256, 0, stream>>>(Wh16, xp, lengths, ghbuf, cbuf, outh, flags, c * TC, TC);
    }
    k_fc<<<Bsz, 64, 0, stream>>>(outh, fc_w, fc_b, out);
}

// Round 14
// 5754.059 us; speedup vs baseline: 1.0058x; 1.0058x over previous
//
#include <hip/hip_runtime.h>
#include <math.h>

#define Bsz 128
#define Tsz 512
#define Esz 512
#define Hsz 1024
#define G4H 4096
#define Vsz 32000
#define NB  64           // lstm blocks (fat: 512 thr, 16 j-cols each)
#define BH  (Bsz * Hsz)
#define XPS 68           // padded xps row stride (shorts)

typedef __attribute__((ext_vector_type(8))) short short8;
typedef __attribute__((ext_vector_type(4))) short short4v;
typedef __attribute__((ext_vector_type(8))) __bf16 bf16x8;
typedef __attribute__((ext_vector_type(4))) float f32x4;
typedef __attribute__((ext_vector_type(4))) unsigned int uint4v;

__device__ inline unsigned short f2bf(float f) {
    unsigned u = __float_as_uint(f);
    u += 0x7fffu + ((u >> 16) & 1u);   // RTNE
    return (unsigned short)(u >> 16);
}
__device__ inline float bf2f(unsigned short s) {
    return __uint_as_float(((unsigned)s) << 16);
}
__device__ inline f32x4 mfma16(short8 a, short8 b, f32x4 c) {
    return __builtin_amdgcn_mfma_f32_16x16x32_bf16(
        __builtin_bit_cast(bf16x8, a), __builtin_bit_cast(bf16x8, b), c, 0, 0, 0);
}

// async 16B loads; early-clobber so dst never aliases addr regs
#define GLD16P(dst, p)  asm volatile("global_load_dwordx4 %0, %1, off"         : "=&v"(dst) : "v"(p))
#define GLD16L2(dst, p) asm volatile("global_load_dwordx4 %0, %1, off sc0"     : "=&v"(dst) : "v"(p))
#define GLD16M(dst, p)  asm volatile("global_load_dwordx4 %0, %1, off sc0 sc1" : "=&v"(dst) : "v"(p))
// write-through-to-L2 store (bypass L1 retention; stays XCD-local)
#define ST16L2(p, v)    asm volatile("global_store_dwordx4 %0, %1, off sc0" :: "v"(p), "v"(v) : "memory")

#define WAITVM(n)                                                          \
    do { asm volatile("s_waitcnt vmcnt(" #n ")" ::: "memory");             \
         __builtin_amdgcn_sched_barrier(0); } while (0)

// MALL-coherent scalar flag ops (proven R11)
__device__ inline unsigned ld_flag(const unsigned* p) {
    unsigned r;
    asm volatile("global_load_dword %0, %1, off sc0 sc1\n\ts_waitcnt vmcnt(0)"
                 : "=&v"(r) : "v"(p) : "memory");
    return r;
}
__device__ inline void st_flag(unsigned* p, unsigned v) {
    asm volatile("global_store_dword %0, %1, off sc0 sc1" :: "v"(p), "v"(v) : "memory");
}
// MALL atomic add, returns old (sc0 = return-old, sc1 = device scope)
__device__ inline unsigned atadd_mall(unsigned* p, unsigned v) {
    unsigned old;
    asm volatile("global_atomic_add %0, %1, %2, off sc0 sc1\n\ts_waitcnt vmcnt(0)"
                 : "=&v"(old) : "v"(p), "v"(v) : "memory");
    return old;
}

// ---------------- prep kernels ----------------
__global__ void k_prep_emb(const float* __restrict__ emb, unsigned short* __restrict__ dst) {
    size_t i = (size_t)blockIdx.x * 256 + threadIdx.x;
    if (i < (size_t)Vsz * Esz) dst[i] = f2bf(i < Esz ? 0.f : emb[i]);  // row 0 = PAD -> 0
}

__global__ void k_prep_w(const float* __restrict__ wi, const float* __restrict__ wf,
                         const float* __restrict__ wg, const float* __restrict__ wo,
                         int ncols, unsigned short* __restrict__ dst) {
    size_t i = (size_t)blockIdx.x * 256 + threadIdx.x;
    size_t per = (size_t)Hsz * ncols;
    if (i < 4 * per) {
        int g = (int)(i / per);
        size_t rem = i - (size_t)g * per;
        const float* src = g == 0 ? wi : g == 1 ? wf : g == 2 ? wg : wo;
        dst[i] = f2bf(src[rem]);
    }
}

__global__ void k_prep_misc(const float* __restrict__ bi, const float* __restrict__ bff,
                            const float* __restrict__ bg, const float* __restrict__ bo,
                            float* __restrict__ b4, unsigned short* __restrict__ ghbuf,
                            unsigned short* __restrict__ xcopy,
                            float* __restrict__ cbuf, float* __restrict__ outh,
                            unsigned* __restrict__ flags, unsigned* __restrict__ flags2,
                            unsigned* __restrict__ regflags, unsigned* __restrict__ xcdcnt) {
    size_t i = (size_t)blockIdx.x * 256 + threadIdx.x;
    if (i < G4H) {
        const float* src = i < Hsz ? bi : i < 2 * Hsz ? bff : i < 3 * Hsz ? bg : bo;
        b4[i] = src[i & (Hsz - 1)];
    }
    if (i < 2 * (size_t)BH) ghbuf[i] = 0;
    if (i < 16 * (size_t)BH) xcopy[i] = 0;     // [8 xcd][2 parity][BH]
    if (i < (size_t)BH) { cbuf[i] = 0.f; outh[i] = 0.f; }
    if (i < NB * 32) { flags[i] = 0u; flags2[i] = 0u; regflags[i] = 0u; }
    if (i < 128) xcdcnt[i] = 0u;               // [16 launches][8 xcds]
}

// ---------------- xp = emb[x] @ Wi^T + b  (layout [t'][bk64][b][jj16][gate4]) ----------------
__global__ __launch_bounds__(256, 2) void xp_gemm(
    const unsigned short* __restrict__ emb16, const unsigned short* __restrict__ Wi16,
    const float* __restrict__ b4, const int* __restrict__ x,
    unsigned short* __restrict__ xp, int t_base)
{
    const int tp = blockIdx.x;
    const int n0 = blockIdx.y * 128;
    const int tid = threadIdx.x;
    const int w = tid >> 6, l = tid & 63;
    const int wm = w >> 1, wn = w & 1;
    const int lr = l & 15, lk = l >> 4;

    const unsigned short* arow[4];
    #pragma unroll
    for (int mt = 0; mt < 4; ++mt) {
        int b = wm * 64 + mt * 16 + lr;
        int xv = x[b * Tsz + t_base + tp];
        arow[mt] = emb16 + (size_t)xv * Esz + lk * 8;
    }
    const unsigned short* brow[4];
    #pragma unroll
    for (int nt = 0; nt < 4; ++nt) {
        int n = n0 + wn * 64 + nt * 16 + lr;
        brow[nt] = Wi16 + (size_t)n * Esz + lk * 8;
    }
    f32x4 acc[4][4] = {};
    #pragma unroll 2
    for (int k0 = 0; k0 < Esz; k0 += 32) {
        short8 av[4], bv[4];
        #pragma unroll
        for (int mt = 0; mt < 4; ++mt) av[mt] = *(const short8*)(arow[mt] + k0);
        #pragma unroll
        for (int nt = 0; nt < 4; ++nt) bv[nt] = *(const short8*)(brow[nt] + k0);
        #pragma unroll
        for (int mt = 0; mt < 4; ++mt)
            #pragma unroll
            for (int nt = 0; nt < 4; ++nt)
                acc[mt][nt] = mfma16(av[mt], bv[nt], acc[mt][nt]);
    }
    #pragma unroll
    for (int nt = 0; nt < 4; ++nt) {
        int n = n0 + wn * 64 + nt * 16 + lr;
        float bias = b4[n];
        int g = n >> 10, j = n & 1023;
        int bk = j >> 4, jj = j & 15;
        #pragma unroll
        for (int mt = 0; mt < 4; ++mt) {
            #pragma unroll
            for (int r = 0; r < 4; ++r) {
                int b = wm * 64 + mt * 16 + lk * 4 + r;
                xp[((size_t)tp * NB + bk) * (Bsz * 64) + b * 64 + jj * 4 + g] =
                    f2bf(acc[mt][nt][r] + bias);
            }
        }
    }
}

// ---------------- fused recurrence ----------------
// R11 compute (64 blocks x 8 waves, 16x16x32 MFMA, natural-layout Whs) with
// per-XCD h staging: per step, h slabs go to MALL once (sc0sc1), sync-A, then
// each XCD imports the full 256KB ONCE into its private xcopy[myx] (MALL read
// -> sc0 L2 write-through), sync-B; compute A-loads are sc0 L2 hits.
// All control ops are the R11-proven sc0sc1 flag pattern (monotone seqnos).
__global__ __launch_bounds__(512, 1) void lstm_steps(
    const unsigned short* __restrict__ Wh16,
    const unsigned short* __restrict__ xp,    // [T'][NB][b][16][4] bf16
    const int* __restrict__ lengths,
    unsigned short* __restrict__ ghbuf,       // [2][64][128][16] bf16 (MALL exchange)
    unsigned short* __restrict__ xcopy,       // [8][2][64][128][16] bf16 (XCD-private)
    float* __restrict__ cbuf,
    float* __restrict__ outh,
    unsigned* __restrict__ flags,             // [64] sync-A seqno, stride 32 u32
    unsigned* __restrict__ flags2,            // [64] sync-B seqno
    unsigned* __restrict__ regflags,          // [64] registration barrier
    unsigned* __restrict__ xcdcnt,            // [16][8] per-launch registration
    int launch_c, int t0, int nsteps)
{
    __shared__ unsigned short Whs[64][1032];   // 129 KB
    __shared__ unsigned short xps[Bsz * XPS];  // 17 KB
    __shared__ unsigned short hls[Bsz * 16];   // 4 KB
    __shared__ int shx[3];                     // myx, rank, n_x
    const int tid = threadIdx.x;
    const int blk = blockIdx.x;
    const int j0 = blk * 16;

    // stage Wh slice: local row n -> gate n>>4, col j0+(n&15); natural group order
    for (int idx = tid; idx < 64 * 128; idx += 512) {
        int n = idx >> 7, gq = idx & 127;
        int grow = (n >> 4) * Hsz + j0 + (n & 15);
        *(short8*)&Whs[n][gq << 3] =
            *(const short8*)(Wh16 + (size_t)grow * Hsz + gq * 8);
    }

    const int w = tid >> 6, l = tid & 63, lr = l & 15, lk = l >> 4;

    int lenr[4];
    float creg[4];
    #pragma unroll
    for (int r = 0; r < 4; ++r) {
        int b = 16 * w + 4 * lk + r;
        lenr[r] = lengths[b];
        creg[r] = cbuf[(size_t)b * Hsz + j0 + lr];
    }

    // ---- startup: XCD discovery + registration (proven flag pattern) ----
    if (tid == 0) {
        unsigned xg;
        asm volatile("s_getreg_b32 %0, hwreg(HW_REG_XCC_ID)" : "=s"(xg));
        xg &= 7u;
        unsigned rk = atadd_mall(&xcdcnt[launch_c * 8 + xg], 1u);
        shx[0] = (int)xg;
        shx[1] = (int)rk;
        st_flag(&regflags[blk * 32], (unsigned)(launch_c + 1));
    }
    {
        const unsigned* fp = &regflags[(tid & 63) * 32];
        while (ld_flag(fp) < (unsigned)(launch_c + 1)) __builtin_amdgcn_s_sleep(1);
    }
    __syncthreads();
    if (tid == 0) shx[2] = (int)ld_flag(&xcdcnt[launch_c * 8 + shx[0]]);
    __syncthreads();
    const int myx = shx[0], rank = shx[1], n_x = shx[2];

    // prologue: stage xp slice for s=0
    {
        const short8* sp = (const short8*)(xp + (size_t)blk * (Bsz * 64));
        int xb = tid >> 2, xq = tid & 3;
        *(short8*)&xps[xb * XPS + xq * 16]     = sp[tid * 2];
        *(short8*)&xps[xb * XPS + xq * 16 + 8] = sp[tid * 2 + 1];
    }
    __syncthreads();

    // A-load lane base (within a 256KB h buffer): slab*2048 + row*16 + k-part
    const int hb_off = (lk >> 1) * 2048 + (lk & 1) * 8 + (16 * w + lr) * 16;

#define ISSUE_CHUNK(buf, kc_) do {                                         \
        GLD16L2(buf[0], hb + (kc_) * 16384 + 0);                           \
        GLD16L2(buf[1], hb + (kc_) * 16384 + 4096);                        \
        GLD16L2(buf[2], hb + (kc_) * 16384 + 8192);                        \
        GLD16L2(buf[3], hb + (kc_) * 16384 + 12288);                       \
    } while (0)

#define CONSUME(buf, kc_) do {                                             \
        _Pragma("unroll")                                                  \
        for (int ks_ = 0; ks_ < 4; ++ks_) {                                \
            short8 a_ = __builtin_bit_cast(short8, buf[ks_]);              \
            const int go_ = ((kc_) * 16 + ks_ * 4 + lk) << 3;              \
            _Pragma("unroll")                                              \
            for (int nt_ = 0; nt_ < 4; ++nt_) {                            \
                short8 bv_ = *(const short8*)&Whs[nt_ * 16 + lr][go_];     \
                acc[nt_] = mfma16(a_, bv_, acc[nt_]);                      \
            }                                                              \
        }                                                                  \
    } while (0)

    for (int s = 0; s < nsteps; ++s) {
        const int t = t0 + s;
        // A-operand from MY XCD's L2 copy (imported last step / zeroed by prep)
        const unsigned short* hb = xcopy + ((size_t)myx * 2 + (t & 1)) * BH + hb_off;
        int sn = (s + 1 < nsteps) ? s + 1 : s;
        const unsigned short* xpn = xp + ((size_t)sn * NB + blk) * (Bsz * 64) + tid * 16;

        f32x4 acc[4] = {};
        uint4v A[4], Bb[4], xr0, xr1;
        // wait-then-consume pipeline, 4 loads/chunk, 2 chunks in flight (R9-proven)
        ISSUE_CHUNK(A, 0);  ISSUE_CHUNK(Bb, 1);
        WAITVM(4);  CONSUME(A, 0);   ISSUE_CHUNK(A, 2);
        WAITVM(4);  CONSUME(Bb, 1);  ISSUE_CHUNK(Bb, 3);
        WAITVM(4);  CONSUME(A, 2);   ISSUE_CHUNK(A, 4);
        WAITVM(4);  CONSUME(Bb, 3);  ISSUE_CHUNK(Bb, 5);
        WAITVM(4);  CONSUME(A, 4);   ISSUE_CHUNK(A, 6);
        WAITVM(4);  CONSUME(Bb, 5);  ISSUE_CHUNK(Bb, 7);
        GLD16P(xr0, xpn); GLD16P(xr1, xpn + 8);
        WAITVM(6);  CONSUME(A, 6);
        WAITVM(2);  CONSUME(Bb, 7);            // xr may still be in flight

        // gates: lane owns (b=16w+4lk+r, j=j0+lr); all 4 gates in acc[nt][r]
        #pragma unroll
        for (int r = 0; r < 4; ++r) {
            int b = 16 * w + 4 * lk + r;
            short4v xg4 = *(const short4v*)&xps[b * XPS + lr * 4];
            float zi = acc[0][r] + bf2f((unsigned short)xg4[0]);
            float zf = acc[1][r] + bf2f((unsigned short)xg4[1]);
            float zg = acc[2][r] + bf2f((unsigned short)xg4[2]);
            float zo = acc[3][r] + bf2f((unsigned short)xg4[3]);
            float it = 1.f / (1.f + __expf(-zi));
            float ft = 1.f / (1.f + __expf(-zf));
            float gt = tanhf(zg);
            float ot = 1.f / (1.f + __expf(-zo));
            float c = ft * creg[r] + it * gt;
            creg[r] = c;
            float h = ot * tanhf(c);
            if (lenr[r] == t + 1) outh[(size_t)b * Hsz + j0 + lr] = h;
            hls[b * 16 + lr] = f2bf(h);
        }
        __syncthreads();   // hls complete (all waves); xps reads for step s done

        // coalesced h slab store: one contiguous 4KB burst, write-through to MALL
        unsigned short* ghn = ghbuf + (size_t)((t + 1) & 1) * BH;
        if (tid < 256) {
            short8 hv8 = *(const short8*)&hls[tid * 8];
            unsigned short* hd = ghn + (size_t)blk * 2048 + tid * 8;
            asm volatile("global_store_dwordx4 %0, %1, off sc0 sc1"
                         :: "v"(hd), "v"(__builtin_bit_cast(uint4v, hv8)) : "memory");
        }

        // drain own stores + xr, then restage xps from prefetched regs
        WAITVM(0);
        {
            int xb = tid >> 2, xq = tid & 3;
            *(short8*)&xps[xb * XPS + xq * 16]     = __builtin_bit_cast(short8, xr0);
            *(short8*)&xps[xb * XPS + xq * 16 + 8] = __builtin_bit_cast(short8, xr1);
        }
        __syncthreads();   // ALL threads' slab stores ACKed at MALL; xps staged

        // ---- sync A: all h(t+1) slabs at MALL ----
        if (tid == 0) st_flag(&flags[blk * 32], (unsigned)(t + 1));
        {
            const unsigned* fp = &flags[(tid & 63) * 32];
            while (ld_flag(fp) < (unsigned)(t + 1)) __builtin_amdgcn_s_sleep(1);
        }
        __syncthreads();

        // ---- import h(t+1): MALL -> my XCD's L2 copy (rank-partitioned) ----
        {
            unsigned short* xdst = xcopy + ((size_t)myx * 2 + ((t + 1) & 1)) * BH;
            for (int p0 = rank; p0 < 32; p0 += n_x * 4) {
                int p1 = p0 + n_x, p2 = p1 + n_x, p3 = p2 + n_x;
                uint4v v0, v1, v2, v3;
                GLD16M(v0, ghn + (size_t)p0 * 4096 + tid * 8);
                if (p1 < 32) GLD16M(v1, ghn + (size_t)p1 * 4096 + tid * 8);
                if (p2 < 32) GLD16M(v2, ghn + (size_t)p2 * 4096 + tid * 8);
                if (p3 < 32) GLD16M(v3, ghn + (size_t)p3 * 4096 + tid * 8);
                WAITVM(0);
                ST16L2(xdst + (size_t)p0 * 4096 + tid * 8, v0);
                if (p1 < 32) ST16L2(xdst + (size_t)p1 * 4096 + tid * 8, v1);
                if (p2 < 32) ST16L2(xdst + (size_t)p2 * 4096 + tid * 8, v2);
                if (p3 < 32) ST16L2(xdst + (size_t)p3 * 4096 + tid * 8, v3);
            }
            WAITVM(0);     // import stores ACKed at L2
        }
        __syncthreads();

        // ---- sync B: all imports done (superset: poll all 64) ----
        if (tid == 0) st_flag(&flags2[blk * 32], (unsigned)(t + 1));
        {
            const unsigned* fp = &flags2[(tid & 63) * 32];
            while (ld_flag(fp) < (unsigned)(t + 1)) __builtin_amdgcn_s_sleep(1);
        }
        __syncthreads();
        __builtin_amdgcn_sched_barrier(0);   // keep next-step loads below the sync
    }

    #pragma unroll
    for (int r = 0; r < 4; ++r) {
        int b = 16 * w + 4 * lk + r;
        cbuf[(size_t)b * Hsz + j0 + lr] = creg[r];
    }
#undef ISSUE_CHUNK
#undef CONSUME
}

// ---------------- final fc ----------------
__global__ __launch_bounds__(64) void k_fc(const float* __restrict__ outh,
                                           const float* __restrict__ fc_w,
                                           const float* __restrict__ fc_b,
                                           float* __restrict__ out) {
    int b = blockIdx.x, l = threadIdx.x;
    float s = 0.f;
    for (int k = l; k < Hsz; k += 64) s += outh[(size_t)b * Hsz + k] * fc_w[k];
    #pragma unroll
    for (int o = 32; o > 0; o >>= 1) s += __shfl_down(s, o);
    if (l == 0) out[b] = s + fc_b[0];
}

extern "C" void kernel_launch(void* const* d_in, const int* in_sizes, int n_in,
                              void* d_out, int out_size, void* d_ws, size_t ws_size,
                              hipStream_t stream) {
    const int* x       = (const int*)d_in[0];
    const int* lengths = (const int*)d_in[1];
    const float* emb   = (const float*)d_in[2];
    const float* W_ii  = (const float*)d_in[3];
    const float* W_hi  = (const float*)d_in[4];
    const float* b_i   = (const float*)d_in[5];
    const float* W_if  = (const float*)d_in[6];
    const float* W_hf  = (const float*)d_in[7];
    const float* b_f   = (const float*)d_in[8];
    const float* W_ig  = (const float*)d_in[9];
    const float* W_hg  = (const float*)d_in[10];
    const float* b_g   = (const float*)d_in[11];
    const float* W_io  = (const float*)d_in[12];
    const float* W_ho  = (const float*)d_in[13];
    const float* b_o   = (const float*)d_in[14];
    const float* fc_w  = (const float*)d_in[15];
    const float* fc_b  = (const float*)d_in[16];
    float* out = (float*)d_out;

    char* ws = (char*)d_ws;
    size_t off = 0;
    auto take = [&](size_t bytes) { size_t o = off; off += (bytes + 255) & ~(size_t)255; return o; };
    unsigned* flags       = (unsigned*)(ws + take((size_t)NB * 128));
    unsigned* flags2      = (unsigned*)(ws + take((size_t)NB * 128));
    unsigned* regflags    = (unsigned*)(ws + take((size_t)NB * 128));
    unsigned* xcdcnt      = (unsigned*)(ws + take(512));
    unsigned short* ghbuf = (unsigned short*)(ws + take((size_t)2 * BH * 2));
    unsigned short* xcopy = (unsigned short*)(ws + take((size_t)16 * BH * 2));
    float* cbuf           = (float*)(ws + take((size_t)BH * 4));
    float* outh           = (float*)(ws + take((size_t)BH * 4));
    float* b4             = (float*)(ws + take((size_t)G4H * 4));
    unsigned short* Wi16  = (unsigned short*)(ws + take((size_t)G4H * Esz * 2));
    unsigned short* Wh16  = (unsigned short*)(ws + take((size_t)G4H * Hsz * 2));
    unsigned short* emb16 = (unsigned short*)(ws + take((size_t)Vsz * Esz * 2));
    size_t fixed = off;

    int TC = 128;
    while (TC > 1 && fixed + (size_t)TC * Bsz * G4H * 2 > ws_size) TC >>= 1;
    unsigned short* xp = (unsigned short*)(ws + take((size_t)TC * Bsz * G4H * 2));

    k_prep_emb<<<(Vsz * Esz + 255) / 256, 256, 0, stream>>>(emb, emb16);
    k_prep_w<<<(4 * Hsz * Esz + 255) / 256, 256, 0, stream>>>(W_ii, W_if, W_ig, W_io, Esz, Wi16);
    k_prep_w<<<(4 * Hsz * Hsz + 255) / 256, 256, 0, stream>>>(W_hi, W_hf, W_hg, W_ho, Hsz, Wh16);
    k_prep_misc<<<(16 * BH + 255) / 256, 256, 0, stream>>>(
        b_i, b_f, b_g, b_o, b4, ghbuf, xcopy, cbuf, outh, flags, flags2, regflags, xcdcnt);

    for (int c = 0; c < Tsz / TC; ++c) {
        dim3 g(TC, 32);
        xp_gemm<<<g, 256, 0, stream>>>(emb16, Wi16, b4, x, xp, c * TC);
        lstm_steps<<<NB, 512, 0, stream>>>(Wh16, xp, lengths, ghbuf, xcopy, cbuf, outh,
                                           flags, flags2, regflags, xcdcnt,
                                           c, c * TC, TC);
    }
    k_fc<<<Bsz, 64, 0, stream>>>(outh, fc_w, fc_b, out);
}

// Round 15
// 3906.002 us; speedup vs baseline: 1.4817x; 1.4731x over previous
//
#include <hip/hip_runtime.h>
#include <math.h>

#define Bsz 128
#define Tsz 512
#define Esz 512
#define Hsz 1024
#define G4H 4096
#define Vsz 32000
#define NB  64           // lstm blocks (fat: 512 thr, 16 j-cols each)
#define BH  (Bsz * Hsz)
#define XPS 68           // padded xps row stride (shorts)

typedef __attribute__((ext_vector_type(8))) short short8;
typedef __attribute__((ext_vector_type(4))) short short4v;
typedef __attribute__((ext_vector_type(8))) __bf16 bf16x8;
typedef __attribute__((ext_vector_type(4))) float f32x4;
typedef __attribute__((ext_vector_type(4))) unsigned int uint4v;

__device__ inline unsigned short f2bf(float f) {
    unsigned u = __float_as_uint(f);
    u += 0x7fffu + ((u >> 16) & 1u);   // RTNE
    return (unsigned short)(u >> 16);
}
__device__ inline float bf2f(unsigned short s) {
    return __uint_as_float(((unsigned)s) << 16);
}
__device__ inline f32x4 mfma16(short8 a, short8 b, f32x4 c) {
    return __builtin_amdgcn_mfma_f32_16x16x32_bf16(
        __builtin_bit_cast(bf16x8, a), __builtin_bit_cast(bf16x8, b), c, 0, 0, 0);
}

// async 16B loads; early-clobber so dst never aliases addr regs
#define GLD16P(dst, p)  asm volatile("global_load_dwordx4 %0, %1, off"         : "=&v"(dst) : "v"(p))
#define GLD16C(dst, p)  asm volatile("global_load_dwordx4 %0, %1, off sc0 sc1" : "=&v"(dst) : "v"(p))

#define WAITVM(n)                                                          \
    do { asm volatile("s_waitcnt vmcnt(" #n ")" ::: "memory");             \
         __builtin_amdgcn_sched_barrier(0); } while (0)

// MALL-coherent scalar flag ops (proven R11)
__device__ inline unsigned ld_flag(const unsigned* p) {
    unsigned r;
    asm volatile("global_load_dword %0, %1, off sc0 sc1\n\ts_waitcnt vmcnt(0)"
                 : "=&v"(r) : "v"(p) : "memory");
    return r;
}
__device__ inline void st_flag(unsigned* p, unsigned v) {
    asm volatile("global_store_dword %0, %1, off sc0 sc1" :: "v"(p), "v"(v) : "memory");
}

// ---------------- prep kernels ----------------
__global__ void k_prep_emb(const float* __restrict__ emb, unsigned short* __restrict__ dst) {
    size_t i = (size_t)blockIdx.x * 256 + threadIdx.x;
    if (i < (size_t)Vsz * Esz) dst[i] = f2bf(i < Esz ? 0.f : emb[i]);  // row 0 = PAD -> 0
}

__global__ void k_prep_w(const float* __restrict__ wi, const float* __restrict__ wf,
                         const float* __restrict__ wg, const float* __restrict__ wo,
                         int ncols, unsigned short* __restrict__ dst) {
    size_t i = (size_t)blockIdx.x * 256 + threadIdx.x;
    size_t per = (size_t)Hsz * ncols;
    if (i < 4 * per) {
        int g = (int)(i / per);
        size_t rem = i - (size_t)g * per;
        const float* src = g == 0 ? wi : g == 1 ? wf : g == 2 ? wg : wo;
        dst[i] = f2bf(src[rem]);
    }
}

__global__ void k_prep_misc(const float* __restrict__ bi, const float* __restrict__ bff,
                            const float* __restrict__ bg, const float* __restrict__ bo,
                            float* __restrict__ b4, unsigned short* __restrict__ ghbuf,
                            float* __restrict__ cbuf, float* __restrict__ outh,
                            unsigned* __restrict__ flags) {
    int i = blockIdx.x * 256 + threadIdx.x;
    if (i < G4H) {
        const float* src = i < Hsz ? bi : i < 2 * Hsz ? bff : i < 3 * Hsz ? bg : bo;
        b4[i] = src[i & (Hsz - 1)];
    }
    if (i < 2 * BH) ghbuf[i] = 0;
    if (i < BH) { cbuf[i] = 0.f; outh[i] = 0.f; }
    if (i < NB * 32) flags[i] = 0u;
}

// ---------------- xp = emb[x] @ Wi^T + b  (standalone, chunk-0 prologue) ----------------
__global__ __launch_bounds__(256, 2) void xp_gemm(
    const unsigned short* __restrict__ emb16, const unsigned short* __restrict__ Wi16,
    const float* __restrict__ b4, const int* __restrict__ x,
    unsigned short* __restrict__ xp, int t_base)
{
    const int tp = blockIdx.x;
    const int n0 = blockIdx.y * 128;
    const int tid = threadIdx.x;
    const int w = tid >> 6, l = tid & 63;
    const int wm = w >> 1, wn = w & 1;
    const int lr = l & 15, lk = l >> 4;

    const unsigned short* arow[4];
    #pragma unroll
    for (int mt = 0; mt < 4; ++mt) {
        int b = wm * 64 + mt * 16 + lr;
        int xv = x[b * Tsz + t_base + tp];
        arow[mt] = emb16 + (size_t)xv * Esz + lk * 8;
    }
    const unsigned short* brow[4];
    #pragma unroll
    for (int nt = 0; nt < 4; ++nt) {
        int n = n0 + wn * 64 + nt * 16 + lr;
        brow[nt] = Wi16 + (size_t)n * Esz + lk * 8;
    }
    f32x4 acc[4][4] = {};
    #pragma unroll 2
    for (int k0 = 0; k0 < Esz; k0 += 32) {
        short8 av[4], bv[4];
        #pragma unroll
        for (int mt = 0; mt < 4; ++mt) av[mt] = *(const short8*)(arow[mt] + k0);
        #pragma unroll
        for (int nt = 0; nt < 4; ++nt) bv[nt] = *(const short8*)(brow[nt] + k0);
        #pragma unroll
        for (int mt = 0; mt < 4; ++mt)
            #pragma unroll
            for (int nt = 0; nt < 4; ++nt)
                acc[mt][nt] = mfma16(av[mt], bv[nt], acc[mt][nt]);
    }
    #pragma unroll
    for (int nt = 0; nt < 4; ++nt) {
        int n = n0 + wn * 64 + nt * 16 + lr;
        float bias = b4[n];
        int g = n >> 10, j = n & 1023;
        int bk = j >> 4, jj = j & 15;
        #pragma unroll
        for (int mt = 0; mt < 4; ++mt) {
            #pragma unroll
            for (int r = 0; r < 4; ++r) {
                int b = wm * 64 + mt * 16 + lk * 4 + r;
                xp[((size_t)tp * NB + bk) * (Bsz * 64) + b * 64 + jj * 4 + g] =
                    f2bf(acc[mt][nt][r] + bias);
            }
        }
    }
}

// ---------------- fused: recurrence (blocks < NB) + next-chunk xp GEMM (blocks >= NB) ----------------
// lstm path: bit-identical to R11 (64 blocks x 8 waves, 16x16x32 MFMA, natural
// Whs, sc0sc1 MALL h exchange, decentralized seqno-flag sync).
// gemm path: 192 blocks grid-stride the [TC x 16] 128x256 output tiles of
// xp(chunk c+1) into the other xp buffer. Disjoint buffers -> no interaction.
__global__ __launch_bounds__(512, 1) void lstm_fused(
    const unsigned short* __restrict__ Wh16,
    const unsigned short* __restrict__ xpcur,   // [T'][NB][b][16][4] bf16 (read)
    unsigned short* __restrict__ xpnext,        // same layout (written by gemm path)
    const unsigned short* __restrict__ emb16,
    const unsigned short* __restrict__ Wi16,
    const float* __restrict__ b4,
    const int* __restrict__ x,
    const int* __restrict__ lengths,
    unsigned short* __restrict__ ghbuf,         // [2][64][128][16] bf16 double buffer
    float* __restrict__ cbuf,
    float* __restrict__ outh,
    unsigned* __restrict__ flags,               // [64] seqno flags, stride 32 u32
    int t0, int nsteps, int gt_base, int do_gemm)
{
    __shared__ unsigned short Whs[64][1032];   // 129 KB (forces 1 block/CU, both paths)
    __shared__ unsigned short xps[Bsz * XPS];  // 17 KB
    __shared__ unsigned short hls[Bsz * 16];   // 4 KB
    const int tid = threadIdx.x;
    const int blk = blockIdx.x;

    if (blk >= NB) {
        // ================= gemm path: xp for chunk c+1 =================
        if (!do_gemm) return;
        const int gb = blk - NB;
        const int G = (int)gridDim.x - NB;
        const int w = tid >> 6, l = tid & 63;
        const int wm = w >> 2, wn = w & 3;       // 8 waves: 2(M) x 4(N), tile 128x256
        const int lr = l & 15, lk = l >> 4;
        const int njobs = nsteps * 16;           // nsteps timesteps x 16 n-blocks(256)
        for (int job = gb; job < njobs; job += G) {
            int tp = job >> 4;
            int n0 = (job & 15) * 256;
            const unsigned short* arow[4];
            #pragma unroll
            for (int mt = 0; mt < 4; ++mt) {
                int b = wm * 64 + mt * 16 + lr;
                int xv = x[b * Tsz + gt_base + tp];
                arow[mt] = emb16 + (size_t)xv * Esz + lk * 8;
            }
            const unsigned short* brow[4];
            #pragma unroll
            for (int nt = 0; nt < 4; ++nt) {
                int n = n0 + wn * 64 + nt * 16 + lr;
                brow[nt] = Wi16 + (size_t)n * Esz + lk * 8;
            }
            f32x4 acc[4][4] = {};
            #pragma unroll 2
            for (int k0 = 0; k0 < Esz; k0 += 32) {
                short8 av[4], bv[4];
                #pragma unroll
                for (int mt = 0; mt < 4; ++mt) av[mt] = *(const short8*)(arow[mt] + k0);
                #pragma unroll
                for (int nt = 0; nt < 4; ++nt) bv[nt] = *(const short8*)(brow[nt] + k0);
                #pragma unroll
                for (int mt = 0; mt < 4; ++mt)
                    #pragma unroll
                    for (int nt = 0; nt < 4; ++nt)
                        acc[mt][nt] = mfma16(av[mt], bv[nt], acc[mt][nt]);
            }
            #pragma unroll
            for (int nt = 0; nt < 4; ++nt) {
                int n = n0 + wn * 64 + nt * 16 + lr;
                float bias = b4[n];
                int g = n >> 10, j = n & 1023;
                int bk = j >> 4, jj = j & 15;
                #pragma unroll
                for (int mt = 0; mt < 4; ++mt) {
                    #pragma unroll
                    for (int r = 0; r < 4; ++r) {
                        int b = wm * 64 + mt * 16 + lk * 4 + r;
                        xpnext[((size_t)tp * NB + bk) * (Bsz * 64) + b * 64 + jj * 4 + g] =
                            f2bf(acc[mt][nt][r] + bias);
                    }
                }
            }
        }
        return;
    }

    // ================= lstm path: bit-identical to R11 =================
    const int j0 = blk * 16;

    for (int idx = tid; idx < 64 * 128; idx += 512) {
        int n = idx >> 7, gq = idx & 127;
        int grow = (n >> 4) * Hsz + j0 + (n & 15);
        *(short8*)&Whs[n][gq << 3] =
            *(const short8*)(Wh16 + (size_t)grow * Hsz + gq * 8);
    }

    const int w = tid >> 6, l = tid & 63, lr = l & 15, lk = l >> 4;

    int lenr[4];
    float creg[4];
    #pragma unroll
    for (int r = 0; r < 4; ++r) {
        int b = 16 * w + 4 * lk + r;
        lenr[r] = lengths[b];
        creg[r] = cbuf[(size_t)b * Hsz + j0 + lr];
    }

    // prologue: stage xp slice for s=0
    {
        const short8* sp = (const short8*)(xpcur + (size_t)blk * (Bsz * 64));
        int xb = tid >> 2, xq = tid & 3;
        *(short8*)&xps[xb * XPS + xq * 16]     = sp[tid * 2];
        *(short8*)&xps[xb * XPS + xq * 16 + 8] = sp[tid * 2 + 1];
    }
    __syncthreads();

    const int hb_off = (lk >> 1) * 2048 + (lk & 1) * 8 + (16 * w + lr) * 16;

#define ISSUE_CHUNK(buf, kc_) do {                                         \
        GLD16C(buf[0], hb + (kc_) * 16384 + 0);                            \
        GLD16C(buf[1], hb + (kc_) * 16384 + 4096);                         \
        GLD16C(buf[2], hb + (kc_) * 16384 + 8192);                         \
        GLD16C(buf[3], hb + (kc_) * 16384 + 12288);                        \
    } while (0)

#define CONSUME(buf, kc_) do {                                             \
        _Pragma("unroll")                                                  \
        for (int ks_ = 0; ks_ < 4; ++ks_) {                                \
            short8 a_ = __builtin_bit_cast(short8, buf[ks_]);              \
            const int go_ = ((kc_) * 16 + ks_ * 4 + lk) << 3;              \
            _Pragma("unroll")                                              \
            for (int nt_ = 0; nt_ < 4; ++nt_) {                            \
                short8 bv_ = *(const short8*)&Whs[nt_ * 16 + lr][go_];     \
                acc[nt_] = mfma16(a_, bv_, acc[nt_]);                      \
            }                                                              \
        }                                                                  \
    } while (0)

    for (int s = 0; s < nsteps; ++s) {
        const int t = t0 + s;
        const unsigned short* hb = ghbuf + (size_t)(t & 1) * BH + hb_off;
        int sn = (s + 1 < nsteps) ? s + 1 : s;
        const unsigned short* xpn = xpcur + ((size_t)sn * NB + blk) * (Bsz * 64) + tid * 16;

        f32x4 acc[4] = {};
        uint4v A[4], Bb[4], xr0, xr1;
        ISSUE_CHUNK(A, 0);  ISSUE_CHUNK(Bb, 1);
        WAITVM(4);  CONSUME(A, 0);   ISSUE_CHUNK(A, 2);
        WAITVM(4);  CONSUME(Bb, 1);  ISSUE_CHUNK(Bb, 3);
        WAITVM(4);  CONSUME(A, 2);   ISSUE_CHUNK(A, 4);
        WAITVM(4);  CONSUME(Bb, 3);  ISSUE_CHUNK(Bb, 5);
        WAITVM(4);  CONSUME(A, 4);   ISSUE_CHUNK(A, 6);
        WAITVM(4);  CONSUME(Bb, 5);  ISSUE_CHUNK(Bb, 7);
        GLD16P(xr0, xpn); GLD16P(xr1, xpn + 8);
        WAITVM(6);  CONSUME(A, 6);
        WAITVM(2);  CONSUME(Bb, 7);            // xr may still be in flight

        #pragma unroll
        for (int r = 0; r < 4; ++r) {
            int b = 16 * w + 4 * lk + r;
            short4v xg4 = *(const short4v*)&xps[b * XPS + lr * 4];
            float zi = acc[0][r] + bf2f((unsigned short)xg4[0]);
            float zf = acc[1][r] + bf2f((unsigned short)xg4[1]);
            float zg = acc[2][r] + bf2f((unsigned short)xg4[2]);
            float zo = acc[3][r] + bf2f((unsigned short)xg4[3]);
            float it = 1.f / (1.f + __expf(-zi));
            float ft = 1.f / (1.f + __expf(-zf));
            float gt = tanhf(zg);
            float ot = 1.f / (1.f + __expf(-zo));
            float c = ft * creg[r] + it * gt;
            creg[r] = c;
            float h = ot * tanhf(c);
            if (lenr[r] == t + 1) outh[(size_t)b * Hsz + j0 + lr] = h;
            hls[b * 16 + lr] = f2bf(h);
        }
        __syncthreads();   // hls complete (all waves); xps reads for step s done

        unsigned short* ghn = ghbuf + (size_t)((t + 1) & 1) * BH;
        if (tid < 256) {
            short8 hv8 = *(const short8*)&hls[tid * 8];
            unsigned short* hd = ghn + (size_t)blk * 2048 + tid * 8;
            asm volatile("global_store_dwordx4 %0, %1, off sc0 sc1"
                         :: "v"(hd), "v"(__builtin_bit_cast(uint4v, hv8)) : "memory");
        }

        WAITVM(0);
        {
            int xb = tid >> 2, xq = tid & 3;
            *(short8*)&xps[xb * XPS + xq * 16]     = __builtin_bit_cast(short8, xr0);
            *(short8*)&xps[xb * XPS + xq * 16 + 8] = __builtin_bit_cast(short8, xr1);
        }
        __syncthreads();   // ALL threads' slab stores ACKed at MALL; xps staged

        if (tid == 0) st_flag(&flags[blk * 32], (unsigned)(t + 1));
        {
            const unsigned* fp = &flags[(tid & 63) * 32];
            while (ld_flag(fp) < (unsigned)(t + 1)) __builtin_amdgcn_s_sleep(1);
        }
        __syncthreads();
        __builtin_amdgcn_sched_barrier(0);
    }

    #pragma unroll
    for (int r = 0; r < 4; ++r) {
        int b = 16 * w + 4 * lk + r;
        cbuf[(size_t)b * Hsz + j0 + lr] = creg[r];
    }
#undef ISSUE_CHUNK
#undef CONSUME
}

// ---------------- final fc ----------------
__global__ __launch_bounds__(64) void k_fc(const float* __restrict__ outh,
                                           const float* __restrict__ fc_w,
                                           const float* __restrict__ fc_b,
                                           float* __restrict__ out) {
    int b = blockIdx.x, l = threadIdx.x;
    float s = 0.f;
    for (int k = l; k < Hsz; k += 64) s += outh[(size_t)b * Hsz + k] * fc_w[k];
    #pragma unroll
    for (int o = 32; o > 0; o >>= 1) s += __shfl_down(s, o);
    if (l == 0) out[b] = s + fc_b[0];
}

extern "C" void kernel_launch(void* const* d_in, const int* in_sizes, int n_in,
                              void* d_out, int out_size, void* d_ws, size_t ws_size,
                              hipStream_t stream) {
    const int* x       = (const int*)d_in[0];
    const int* lengths = (const int*)d_in[1];
    const float* emb   = (const float*)d_in[2];
    const float* W_ii  = (const float*)d_in[3];
    const float* W_hi  = (const float*)d_in[4];
    const float* b_i   = (const float*)d_in[5];
    const float* W_if  = (const float*)d_in[6];
    const float* W_hf  = (const float*)d_in[7];
    const float* b_f   = (const float*)d_in[8];
    const float* W_ig  = (const float*)d_in[9];
    const float* W_hg  = (const float*)d_in[10];
    const float* b_g   = (const float*)d_in[11];
    const float* W_io  = (const float*)d_in[12];
    const float* W_ho  = (const float*)d_in[13];
    const float* b_o   = (const float*)d_in[14];
    const float* fc_w  = (const float*)d_in[15];
    const float* fc_b  = (const float*)d_in[16];
    float* out = (float*)d_out;

    char* ws = (char*)d_ws;
    size_t off = 0;
    auto take = [&](size_t bytes) { size_t o = off; off += (bytes + 255) & ~(size_t)255; return o; };
    unsigned* flags       = (unsigned*)(ws + take((size_t)NB * 128));
    unsigned short* ghbuf = (unsigned short*)(ws + take((size_t)2 * BH * 2));
    float* cbuf           = (float*)(ws + take((size_t)BH * 4));
    float* outh           = (float*)(ws + take((size_t)BH * 4));
    float* b4             = (float*)(ws + take((size_t)G4H * 4));
    unsigned short* Wi16  = (unsigned short*)(ws + take((size_t)G4H * Esz * 2));
    unsigned short* Wh16  = (unsigned short*)(ws + take((size_t)G4H * Hsz * 2));
    unsigned short* emb16 = (unsigned short*)(ws + take((size_t)Vsz * Esz * 2));
    size_t fixed = off;

    int TC = 128;   // need TWO xp chunk buffers now
    while (TC > 1 && fixed + 2 * ((size_t)TC * Bsz * G4H * 2 + 256) > ws_size) TC >>= 1;
    unsigned short* xp0 = (unsigned short*)(ws + take((size_t)TC * Bsz * G4H * 2));
    unsigned short* xp1 = (unsigned short*)(ws + take((size_t)TC * Bsz * G4H * 2));
    unsigned short* xpb[2] = {xp0, xp1};

    k_prep_emb<<<(Vsz * Esz + 255) / 256, 256, 0, stream>>>(emb, emb16);
    k_prep_w<<<(4 * Hsz * Esz + 255) / 256, 256, 0, stream>>>(W_ii, W_if, W_ig, W_io, Esz, Wi16);
    k_prep_w<<<(4 * Hsz * Hsz + 255) / 256, 256, 0, stream>>>(W_hi, W_hf, W_hg, W_ho, Hsz, Wh16);
    k_prep_misc<<<(2 * BH + 255) / 256, 256, 0, stream>>>(b_i, b_f, b_g, b_o, b4, ghbuf, cbuf, outh, flags);

    const int nch = Tsz / TC;
    // chunk-0 xp: standalone prologue GEMM
    {
        dim3 g(TC, 32);
        xp_gemm<<<g, 256, 0, stream>>>(emb16, Wi16, b4, x, xp0, 0);
    }
    for (int c = 0; c < nch; ++c) {
        lstm_fused<<<256, 512, 0, stream>>>(
            Wh16, xpb[c & 1], xpb[(c + 1) & 1], emb16, Wi16, b4, x,
            lengths, ghbuf, cbuf, outh, flags,
            c * TC, TC, (c + 1) * TC, (c + 1 < nch) ? 1 : 0);
    }
    k_fc<<<Bsz, 64, 0, stream>>>(outh, fc_w, fc_b, out);
}